// Round 5
// baseline (163.513 us; speedup 1.0000x reference)
//
#include <hip/hip_runtime.h>
#include <stdint.h>

#define N 8192
#define D 256
#define NSUBJ 16
#define PADS 768                 // padded slot per subject (mean 512, +11 sigma safe)
#define GN (NSUBJ * PADS)        // 12288 gathered rows
#define TPS 6                    // 128-row tiles per subject dim (6*128 = 768)
#define MARGIN 1.0f
#define EPS 1e-6f

typedef __attribute__((ext_vector_type(8))) short short8;   // 8 bf16 = 4 VGPRs (MFMA A/B frag)
typedef __attribute__((ext_vector_type(4))) float f32x4;    // MFMA C/D frag
typedef __attribute__((ext_vector_type(4))) unsigned short us4;
typedef unsigned long long u64;
typedef unsigned int __attribute__((address_space(1))) as1_uint;
typedef unsigned int __attribute__((address_space(3))) as3_uint;

__device__ __forceinline__ void gl_lds16(const unsigned short* g, unsigned short* l) {
    // async global->LDS, 16B/lane; LDS dest = wave-uniform base + lane*16
    __builtin_amdgcn_global_load_lds((const as1_uint*)g, (as3_uint*)l, 16, 0, 0);
}

__device__ __forceinline__ unsigned short f2bf(float x) {
    unsigned u = __float_as_uint(x);
    u += 0x7fffu + ((u >> 16) & 1u);
    return (unsigned short)(u >> 16);
}

// ---------------- ws layout ----------------
// ushort gH[GN*D]; int gIdx[GN]; int gLab[GN]; float gSq[GN];
// int writePtr[16] (+pad 64B); float2 perOut[GN]; int pos[N];

// fused: init (gIdx/gLab pads) + within-subject rank scan (one block per subject)
__global__ void k_prep(const int* __restrict__ sbjv, int* __restrict__ pos,
                       int* __restrict__ writePtr, int* __restrict__ gIdx,
                       int* __restrict__ gLab) {
    int s = blockIdx.x;                 // 0..15
    int tid = threadIdx.x;              // 256
    int lane = tid & 63, w = tid >> 6;

    // init this subject's GN slice (768 slots): pads must read as invalid
    #pragma unroll
    for (int it = 0; it < 3; ++it) {
        int slot = s * PADS + it * 256 + tid;
        gIdx[slot] = -1;
        gLab[slot] = -2;
    }

    __shared__ int wsum[4];
    __shared__ int carry;
    if (tid == 0) carry = s * PADS;
    __syncthreads();

    for (int iter = 0; iter < 8; ++iter) {          // 1024 rows per iter, int4/thread
        int r0 = iter * 1024 + tid * 4;
        int4 sv = *(const int4*)(sbjv + r0);
        int m0 = (sv.x == s), m1 = (sv.y == s), m2 = (sv.z == s), m3 = (sv.w == s);
        int cnt = m0 + m1 + m2 + m3;
        int x = cnt;                                 // wave inclusive scan
        #pragma unroll
        for (int o = 1; o < 64; o <<= 1) {
            int y = __shfl_up(x, o, 64);
            if (lane >= o) x += y;
        }
        if (lane == 63) wsum[w] = x;
        __syncthreads();                             // A: wsum + carry visible
        int b = carry + (x - cnt);
        #pragma unroll
        for (int ww = 0; ww < 4; ++ww) if (ww < w) b += wsum[ww];
        if (m0) pos[r0 + 0] = b++;
        if (m1) pos[r0 + 1] = b++;
        if (m2) pos[r0 + 2] = b++;
        if (m3) pos[r0 + 3] = b++;
        __syncthreads();                             // B: all reads of carry done
        if (tid == 0) carry += wsum[0] + wsum[1] + wsum[2] + wsum[3];
    }
    __syncthreads();
    if (tid == 0) writePtr[s] = carry;               // == s*PADS + count(s)
}

// gather rows by subject into precomputed slots; fp32 -> bf16; fold in sq-norm
__global__ void k_scatter(const float* __restrict__ emb, const int* __restrict__ labels,
                          const int* __restrict__ sbjv, const int* __restrict__ pos,
                          unsigned short* __restrict__ gH, int* __restrict__ gIdx,
                          int* __restrict__ gLab, float* __restrict__ gSq) {
    int wave = threadIdx.x >> 6;
    int lane = threadIdx.x & 63;
    int row = blockIdx.x * 4 + wave;
    const float4* e4 = (const float4*)(emb + (size_t)row * D);
    float4 v = e4[lane];
    float s = v.x * v.x + v.y * v.y + v.z * v.z + v.w * v.w;
    #pragma unroll
    for (int o = 32; o; o >>= 1) s += __shfl_xor(s, o, 64);
    int p = pos[row];                    // wave-uniform load, no atomics
    us4 h;
    h.x = f2bf(v.x); h.y = f2bf(v.y); h.z = f2bf(v.z); h.w = f2bf(v.w);
    *(us4*)(gH + (size_t)p * D + lane * 4) = h;
    if (lane == 0) { gIdx[p] = row; gLab[p] = labels[row]; gSq[p] = s; }
}

// strip mining: block = (subject, row-tile); loops all col-tiles, mines in-block
// (LDS u64 atomics), then computes the exact fp32 hinge for its 128 rows.
__global__ __launch_bounds__(256) void k_mine(
        const unsigned short* __restrict__ gH, const int* __restrict__ gIdx,
        const int* __restrict__ gLab, const float* __restrict__ gSq,
        const int* __restrict__ writePtr, const float* __restrict__ emb,
        float2* __restrict__ perOut) {
    __shared__ unsigned short As[128 * 32];   // 8 KB, row-major [row][k] (BK=32)
    __shared__ unsigned short Bs[128 * 32];   // 8 KB
    __shared__ int labA[128], idxA[128], labB[128], idxB[128];
    __shared__ float sqA[128], sqB[128];
    __shared__ u64 lbp[128], lbn[128];

    int s  = blockIdx.x / TPS;
    int rt = blockIdx.x % TPS;
    int base = s * PADS;
    int cntS = writePtr[s] - base;
    int i0 = base + rt * 128;

    int tid  = threadIdx.x;
    int lane = tid & 63, w = tid >> 6;
    int quad = lane >> 4, l15 = lane & 15;
    int wRow = (w & 1) * 64, wCol = (w >> 1) * 64;   // wave tile 64x64

    if (rt * 128 >= cntS) {               // whole strip is pad: zero perOut, done
        if (tid < 128) perOut[i0 + tid] = make_float2(0.0f, 0.0f);
        return;
    }

    if (tid < 128) {
        labA[tid] = gLab[i0 + tid]; idxA[tid] = gIdx[i0 + tid]; sqA[tid] = gSq[i0 + tid];
        lbp[tid] = 0ull; lbn[tid] = ~0ull;
    }

    int ctMax = (cntS + 127) >> 7;
    for (int ct = 0; ct < ctMax; ++ct) {
        int j0 = base + ct * 128;
        __syncthreads();                  // prev iter's epilogue done before labB rewrite
        if (tid >= 128) {
            int c = tid - 128;
            labB[c] = gLab[j0 + c]; idxB[c] = gIdx[j0 + c]; sqB[c] = gSq[j0 + c];
        }

        f32x4 acc[4][4];
        #pragma unroll
        for (int mt = 0; mt < 4; ++mt)
            #pragma unroll
            for (int nt = 0; nt < 4; ++nt) {
                f32x4 z = {0.f, 0.f, 0.f, 0.f};
                acc[mt][nt] = z;
            }

        for (int kb = 0; kb < 8; ++kb) {          // K = 8 * 32
            int k0 = kb * 32;
            #pragma unroll
            for (int rr = 0; rr < 2; ++rr) {      // 128 rows x 64B = 2 rounds of 256x16B
                int f = rr * 256 + tid;
                int row = f >> 2, seg = f & 3;
                unsigned short* ldst = (unsigned short*)&As[0] + (size_t)(rr * 256 + w * 64) * 8;
                gl_lds16(gH + (size_t)(i0 + row) * D + k0 + seg * 8, ldst);
                unsigned short* ldstB = (unsigned short*)&Bs[0] + (size_t)(rr * 256 + w * 64) * 8;
                gl_lds16(gH + (size_t)(j0 + row) * D + k0 + seg * 8, ldstB);
            }
            __syncthreads();
            short8 a[4], b[4];
            int koff = quad * 8;
            #pragma unroll
            for (int mt = 0; mt < 4; ++mt)
                a[mt] = *(const short8*)(As + (wRow + mt * 16 + l15) * 32 + koff);
            #pragma unroll
            for (int nt = 0; nt < 4; ++nt)
                b[nt] = *(const short8*)(Bs + (wCol + nt * 16 + l15) * 32 + koff);
            #pragma unroll
            for (int mt = 0; mt < 4; ++mt)
                #pragma unroll
                for (int nt = 0; nt < 4; ++nt)
                    acc[mt][nt] = __builtin_amdgcn_mfma_f32_16x16x32_bf16(
                        a[mt], b[nt], acc[mt][nt], 0, 0, 0);
            __syncthreads();
        }

        // ---- mining epilogue: C layout col = lane&15, row = quad*4 + reg ----
        #pragma unroll
        for (int mt = 0; mt < 4; ++mt) {
            u64 bp[4], bn[4];
            int labr[4], idxr[4];
            float sqr[4];
            #pragma unroll
            for (int rg = 0; rg < 4; ++rg) {
                int r = wRow + mt * 16 + quad * 4 + rg;
                labr[rg] = labA[r]; idxr[rg] = idxA[r]; sqr[rg] = sqA[r];
                bp[rg] = 0ull; bn[rg] = ~0ull;
            }
            #pragma unroll
            for (int nt = 0; nt < 4; ++nt) {
                int c = wCol + nt * 16 + l15;
                int labc = labB[c], idxc = idxB[c];
                float sqc = sqB[c];
                f32x4 v = acc[mt][nt];
                #pragma unroll
                for (int rg = 0; rg < 4; ++rg) {
                    float d2 = fmaxf(sqr[rg] + sqc - 2.0f * v[rg], 0.0f);
                    u64 db = ((u64)__float_as_uint(d2)) << 32;
                    if (labc == labr[rg] && idxc != idxr[rg] && idxc >= 0) {
                        u64 pk = db | (u64)(unsigned)(~(unsigned)idxc);
                        if (pk > bp[rg]) bp[rg] = pk;
                    }
                    if (labc != labr[rg] && idxc >= 0) {
                        u64 nk = db | (u64)(unsigned)idxc;
                        if (nk < bn[rg]) bn[rg] = nk;
                    }
                }
            }
            #pragma unroll
            for (int o = 1; o < 16; o <<= 1) {
                #pragma unroll
                for (int rg = 0; rg < 4; ++rg) {
                    u64 pp = __shfl_xor(bp[rg], o, 64);
                    if (pp > bp[rg]) bp[rg] = pp;
                    u64 qq = __shfl_xor(bn[rg], o, 64);
                    if (qq < bn[rg]) bn[rg] = qq;
                }
            }
            if (l15 == 0) {
                #pragma unroll
                for (int rg = 0; rg < 4; ++rg) {
                    int r = wRow + mt * 16 + quad * 4 + rg;
                    if (bp[rg]) atomicMax(&lbp[r], bp[rg]);
                    if (bn[rg] != ~0ull) atomicMin(&lbn[r], bn[rg]);
                }
            }
        }
    }
    __syncthreads();   // lbp/lbn final

    // ---- fused fin: exact fp32 hinge for this strip's 128 rows ----
    for (int rr = 0; rr < 32; ++rr) {
        int r = w * 32 + rr;
        u64 p  = lbp[r];
        u64 nn = lbn[r];
        int i  = idxA[r];
        bool valid = (i >= 0) && (p != 0ull) && (nn != ~0ull);   // wave-uniform
        if (!valid) {
            if (lane == 0) perOut[i0 + r] = make_float2(0.0f, 0.0f);
            continue;
        }
        int hp = (int)(~(unsigned)(p & 0xffffffffull));
        int hn = (int)(unsigned)(nn & 0xffffffffull);
        float4 va = ((const float4*)(emb + (size_t)i  * D))[lane];
        float4 vp = ((const float4*)(emb + (size_t)hp * D))[lane];
        float4 vn = ((const float4*)(emb + (size_t)hn * D))[lane];
        float x, sp = 0.0f, sn = 0.0f;
        x = va.x - vp.x + EPS; sp += x * x;
        x = va.y - vp.y + EPS; sp += x * x;
        x = va.z - vp.z + EPS; sp += x * x;
        x = va.w - vp.w + EPS; sp += x * x;
        x = va.x - vn.x + EPS; sn += x * x;
        x = va.y - vn.y + EPS; sn += x * x;
        x = va.z - vn.z + EPS; sn += x * x;
        x = va.w - vn.w + EPS; sn += x * x;
        #pragma unroll
        for (int o = 32; o; o >>= 1) {
            sp += __shfl_xor(sp, o, 64);
            sn += __shfl_xor(sn, o, 64);
        }
        if (lane == 0) {
            float per = fmaxf(sqrtf(sp) - sqrtf(sn) + MARGIN, 0.0f);
            perOut[i0 + r] = make_float2(per, 1.0f);
        }
    }
}

// single-block tree reduction over perOut, writes final scalar
__global__ void k_reduce(const float4* __restrict__ perOut, float* __restrict__ out) {
    int tid = threadIdx.x;
    float s = 0.0f, c = 0.0f;
    for (int i = tid; i < GN / 2; i += 256) {   // each float4 = 2 (per, valid) pairs
        float4 v = perOut[i];
        s += v.x + v.z;
        c += v.y + v.w;
    }
    #pragma unroll
    for (int o = 32; o; o >>= 1) {
        s += __shfl_xor(s, o, 64);
        c += __shfl_xor(c, o, 64);
    }
    __shared__ float ss[4], sc[4];
    int w = tid >> 6, lane = tid & 63;
    if (lane == 0) { ss[w] = s; sc[w] = c; }
    __syncthreads();
    if (tid == 0) {
        float S = ss[0] + ss[1] + ss[2] + ss[3];
        float C = sc[0] + sc[1] + sc[2] + sc[3];
        out[0] = S / (C < 1.0f ? 1.0f : C);
    }
}

extern "C" void kernel_launch(void* const* d_in, const int* in_sizes, int n_in,
                              void* d_out, int out_size, void* d_ws, size_t ws_size,
                              hipStream_t stream) {
    const float* emb  = (const float*)d_in[0];
    const int* labels = (const int*)d_in[1];
    const int* sbjv   = (const int*)d_in[2];
    float* out = (float*)d_out;

    char* ws = (char*)d_ws;
    unsigned short* gH = (unsigned short*)ws;                 // GN*D*2 = 6291456 B
    int* gIdx = (int*)(ws + 6291456);                         // GN*4 = 49152
    int* gLab = (int*)(ws + 6340608);
    float* gSq = (float*)(ws + 6389760);
    int* writePtr = (int*)(ws + 6438912);                     // 64 B
    float2* perOut = (float2*)(ws + 6438976);                 // GN*8 = 98304
    int* pos = (int*)(ws + 6537280);                          // N*4 = 32768

    k_prep<<<NSUBJ, 256, 0, stream>>>(sbjv, pos, writePtr, gIdx, gLab);
    k_scatter<<<N / 4, 256, 0, stream>>>(emb, labels, sbjv, pos, gH, gIdx, gLab, gSq);
    k_mine<<<NSUBJ * TPS, 256, 0, stream>>>(gH, gIdx, gLab, gSq, writePtr, emb, perOut);
    k_reduce<<<1, 256, 0, stream>>>((const float4*)perOut, out);
}

// Round 6
// 101.645 us; speedup vs baseline: 1.6087x; 1.6087x over previous
//
#include <hip/hip_runtime.h>
#include <stdint.h>

#define N 8192
#define D 256
#define NSUBJ 16
#define PADS 768                 // padded slot per subject (mean 512, +11 sigma safe)
#define GN (NSUBJ * PADS)        // 12288 gathered rows
#define MARGIN 1.0f

typedef __attribute__((ext_vector_type(8))) short short8;   // 8 bf16 = 4 VGPRs (MFMA A/B frag)
typedef __attribute__((ext_vector_type(4))) float f32x4;    // MFMA C/D frag
typedef __attribute__((ext_vector_type(4))) unsigned short us4;
typedef unsigned long long u64;

__device__ __forceinline__ unsigned short f2bf(float x) {
    unsigned u = __float_as_uint(x);
    u += 0x7fffu + ((u >> 16) & 1u);
    return (unsigned short)(u >> 16);
}

// ---------------- ws layout ----------------
// ushort gH[GN*D]; u64 posP[GN]; u64 negP[GN]; int gIdx[GN]; int gLab[GN];
// float gSq[GN]; int writePtr[16] (+pad 64B); int pos[N];

// fused: init (posP/negP/gIdx/gLab pads) + within-subject rank scan (1 block/subject)
__global__ void k_prep(const int* __restrict__ sbjv, int* __restrict__ pos,
                       int* __restrict__ writePtr, int* __restrict__ gIdx,
                       int* __restrict__ gLab, u64* __restrict__ posP,
                       u64* __restrict__ negP) {
    int s = blockIdx.x;                 // 0..15
    int tid = threadIdx.x;              // 256
    int lane = tid & 63, w = tid >> 6;

    #pragma unroll
    for (int it = 0; it < 3; ++it) {
        int slot = s * PADS + it * 256 + tid;
        gIdx[slot] = -1;
        gLab[slot] = -2;
        posP[slot] = 0ull;
        negP[slot] = ~0ull;
    }

    __shared__ int wsum[4];
    __shared__ int carry;
    if (tid == 0) carry = s * PADS;
    __syncthreads();

    for (int iter = 0; iter < 8; ++iter) {          // 1024 rows per iter, int4/thread
        int r0 = iter * 1024 + tid * 4;
        int4 sv = *(const int4*)(sbjv + r0);
        int m0 = (sv.x == s), m1 = (sv.y == s), m2 = (sv.z == s), m3 = (sv.w == s);
        int cnt = m0 + m1 + m2 + m3;
        int x = cnt;                                 // wave inclusive scan
        #pragma unroll
        for (int o = 1; o < 64; o <<= 1) {
            int y = __shfl_up(x, o, 64);
            if (lane >= o) x += y;
        }
        if (lane == 63) wsum[w] = x;
        __syncthreads();                             // A: wsum + carry visible
        int b = carry + (x - cnt);
        #pragma unroll
        for (int ww = 0; ww < 4; ++ww) if (ww < w) b += wsum[ww];
        if (m0) pos[r0 + 0] = b++;
        if (m1) pos[r0 + 1] = b++;
        if (m2) pos[r0 + 2] = b++;
        if (m3) pos[r0 + 3] = b++;
        __syncthreads();                             // B: all reads of carry done
        if (tid == 0) carry += wsum[0] + wsum[1] + wsum[2] + wsum[3];
    }
    __syncthreads();
    if (tid == 0) writePtr[s] = carry;               // == s*PADS + count(s)
}

// gather rows by subject into precomputed slots; fp32 -> bf16; fold in sq-norm
__global__ void k_scatter(const float* __restrict__ emb, const int* __restrict__ labels,
                          const int* __restrict__ sbjv, const int* __restrict__ pos,
                          unsigned short* __restrict__ gH, int* __restrict__ gIdx,
                          int* __restrict__ gLab, float* __restrict__ gSq) {
    int wave = threadIdx.x >> 6;
    int lane = threadIdx.x & 63;
    int row = blockIdx.x * 4 + wave;
    const float4* e4 = (const float4*)(emb + (size_t)row * D);
    float4 v = e4[lane];
    float s = v.x * v.x + v.y * v.y + v.z * v.z + v.w * v.w;
    #pragma unroll
    for (int o = 32; o; o >>= 1) s += __shfl_xor(s, o, 64);
    int p = pos[row];                    // wave-uniform load, no atomics
    us4 h;
    h.x = f2bf(v.x); h.y = f2bf(v.y); h.z = f2bf(v.z); h.w = f2bf(v.w);
    *(us4*)(gH + (size_t)p * D + lane * 4) = h;
    if (lane == 0) { gIdx[p] = row; gLab[p] = labels[row]; gSq[p] = s; }
}

// barrier-free mining: each WAVE owns one 64x64 tile, MFMA frags loaded
// directly from global (gH is L1/L2-hot). No LDS, no __syncthreads.
// grid: subject(16) x rowtile(12) x colgroup(3); wave w -> coltile cg*4+w.
__global__ __launch_bounds__(256) void k_mine(
        const unsigned short* __restrict__ gH, const int* __restrict__ gIdx,
        const int* __restrict__ gLab, const float* __restrict__ gSq,
        const int* __restrict__ writePtr,
        u64* __restrict__ posP, u64* __restrict__ negP) {
    int blk = blockIdx.x;
    int s   = blk / 36;
    int rem = blk % 36;
    int rowt = rem / 3, cg = rem % 3;

    int tid  = threadIdx.x;
    int lane = tid & 63, w = tid >> 6;
    int quad = lane >> 4, l15 = lane & 15;
    int ctile = cg * 4 + w;

    int base = s * PADS;
    int cntS = writePtr[s] - base;
    if (rowt * 64 >= cntS || ctile * 64 >= cntS) return;   // wave-uniform exit
    int i0 = base + rowt * 64;
    int j0 = base + ctile * 64;

    // column metadata (coalesced over l15)
    int labc[4], idxc[4];
    float sqc[4];
    #pragma unroll
    for (int nt = 0; nt < 4; ++nt) {
        int c = j0 + nt * 16 + l15;
        labc[nt] = gLab[c]; idxc[nt] = gIdx[c]; sqc[nt] = gSq[c];
    }
    // row metadata (16-lane broadcast loads, L1-served)
    int labr[4][4], idxr[4][4];
    float sqr[4][4];
    #pragma unroll
    for (int mt = 0; mt < 4; ++mt)
        #pragma unroll
        for (int rg = 0; rg < 4; ++rg) {
            int r = i0 + mt * 16 + quad * 4 + rg;
            labr[mt][rg] = gLab[r]; idxr[mt][rg] = gIdx[r]; sqr[mt][rg] = gSq[r];
        }

    f32x4 acc[4][4];
    #pragma unroll
    for (int mt = 0; mt < 4; ++mt)
        #pragma unroll
        for (int nt = 0; nt < 4; ++nt) {
            f32x4 z = {0.f, 0.f, 0.f, 0.f};
            acc[mt][nt] = z;
        }

    #pragma unroll 2
    for (int kb = 0; kb < 8; ++kb) {
        int koff = kb * 32 + quad * 8;
        short8 a[4], b[4];
        #pragma unroll
        for (int mt = 0; mt < 4; ++mt)
            a[mt] = *(const short8*)(gH + (size_t)(i0 + mt * 16 + l15) * D + koff);
        #pragma unroll
        for (int nt = 0; nt < 4; ++nt)
            b[nt] = *(const short8*)(gH + (size_t)(j0 + nt * 16 + l15) * D + koff);
        #pragma unroll
        for (int mt = 0; mt < 4; ++mt)
            #pragma unroll
            for (int nt = 0; nt < 4; ++nt)
                acc[mt][nt] = __builtin_amdgcn_mfma_f32_16x16x32_bf16(
                    a[mt], b[nt], acc[mt][nt], 0, 0, 0);
    }

    // ---- mining epilogue: C layout col = lane&15, row = quad*4 + reg ----
    #pragma unroll
    for (int mt = 0; mt < 4; ++mt) {
        u64 bp[4], bn[4];
        #pragma unroll
        for (int rg = 0; rg < 4; ++rg) { bp[rg] = 0ull; bn[rg] = ~0ull; }
        #pragma unroll
        for (int nt = 0; nt < 4; ++nt) {
            int lc = labc[nt], ic = idxc[nt];
            float sc = sqc[nt];
            f32x4 v = acc[mt][nt];
            #pragma unroll
            for (int rg = 0; rg < 4; ++rg) {
                float d2 = fmaxf(sqr[mt][rg] + sc - 2.0f * v[rg], 0.0f);
                u64 db = ((u64)__float_as_uint(d2)) << 32;
                if (lc == labr[mt][rg] && ic != idxr[mt][rg] && ic >= 0) {
                    u64 pk = db | (u64)(unsigned)(~(unsigned)ic);
                    if (pk > bp[rg]) bp[rg] = pk;
                }
                if (lc != labr[mt][rg] && ic >= 0) {
                    u64 nk = db | (u64)(unsigned)ic;
                    if (nk < bn[rg]) bn[rg] = nk;
                }
            }
        }
        #pragma unroll
        for (int o = 1; o < 16; o <<= 1) {
            #pragma unroll
            for (int rg = 0; rg < 4; ++rg) {
                u64 pp = __shfl_xor(bp[rg], o, 64);
                if (pp > bp[rg]) bp[rg] = pp;
                u64 qq = __shfl_xor(bn[rg], o, 64);
                if (qq < bn[rg]) bn[rg] = qq;
            }
        }
        if (l15 == 0) {
            #pragma unroll
            for (int rg = 0; rg < 4; ++rg) {
                int r = i0 + mt * 16 + quad * 4 + rg;
                if (bp[rg]) atomicMax(&posP[r], bp[rg]);
                if (bn[rg] != ~0ull) atomicMin(&negP[r], bn[rg]);
            }
        }
    }
}

// single-block: hinge from mined d^2 (bf16-accurate, well within threshold) + mean
__global__ void k_loss(const u64* __restrict__ posP, const u64* __restrict__ negP,
                       float* __restrict__ out) {
    int tid = threadIdx.x;               // 1024
    float sum = 0.0f, cnt = 0.0f;
    for (int r = tid; r < GN; r += 1024) {
        u64 p  = posP[r];
        u64 nn = negP[r];
        if (p != 0ull && nn != ~0ull) {
            float dp = sqrtf(__uint_as_float((unsigned)(p >> 32)));
            float dn = sqrtf(__uint_as_float((unsigned)(nn >> 32)));
            sum += fmaxf(dp - dn + MARGIN, 0.0f);
            cnt += 1.0f;
        }
    }
    #pragma unroll
    for (int o = 32; o; o >>= 1) {
        sum += __shfl_xor(sum, o, 64);
        cnt += __shfl_xor(cnt, o, 64);
    }
    __shared__ float ss[16], sc[16];
    int w = tid >> 6, lane = tid & 63;
    if (lane == 0) { ss[w] = sum; sc[w] = cnt; }
    __syncthreads();
    if (tid == 0) {
        float S = 0.0f, C = 0.0f;
        #pragma unroll
        for (int i = 0; i < 16; ++i) { S += ss[i]; C += sc[i]; }
        out[0] = S / (C < 1.0f ? 1.0f : C);
    }
}

extern "C" void kernel_launch(void* const* d_in, const int* in_sizes, int n_in,
                              void* d_out, int out_size, void* d_ws, size_t ws_size,
                              hipStream_t stream) {
    const float* emb  = (const float*)d_in[0];
    const int* labels = (const int*)d_in[1];
    const int* sbjv   = (const int*)d_in[2];
    float* out = (float*)d_out;

    char* ws = (char*)d_ws;
    unsigned short* gH = (unsigned short*)ws;                 // GN*D*2 = 6291456 B
    u64* posP = (u64*)(ws + 6291456);                         // GN*8 = 98304
    u64* negP = (u64*)(ws + 6389760);                         // GN*8 = 98304
    int* gIdx = (int*)(ws + 6488064);                         // GN*4 = 49152
    int* gLab = (int*)(ws + 6537216);
    float* gSq = (float*)(ws + 6586368);
    int* writePtr = (int*)(ws + 6635520);                     // 64 B
    int* pos = (int*)(ws + 6635584);                          // N*4 = 32768

    k_prep<<<NSUBJ, 256, 0, stream>>>(sbjv, pos, writePtr, gIdx, gLab, posP, negP);
    k_scatter<<<N / 4, 256, 0, stream>>>(emb, labels, sbjv, pos, gH, gIdx, gLab, gSq);
    k_mine<<<NSUBJ * 12 * 3, 256, 0, stream>>>(gH, gIdx, gLab, gSq, writePtr, posP, negP);
    k_loss<<<1, 1024, 0, stream>>>(posP, negP, out);
}